// Round 15
// baseline (1213.593 us; speedup 1.0000x reference)
//
#include <hip/hip_runtime.h>

// ---------------------------------------------------------------------------
// SimplicialAttentionTransformer — LAYER-MAJOR, CROSS-STREAM-BATCHED.
// Big GEMM (256x256, 8 waves): counted-vmcnt pipeline (A triple-, B double-
// buffered, 160KB LDS) with NO intra-tile barriers — only the per-K-tile
// boundary s_waitcnt vmcnt(4) lgkmcnt(0) + s_barrier. Waves free-run within
// a tile so one wave's MFMA overlaps another's ds_read (m114 overlap).
// Small GEMM (128x128, 4 waves): 2-phase double-buffered (round-7-proven).
// Softmax: online (max,sumexp) fused into scores, 2-stage combine.
// bf16 residual stream; swapped-operand MFMA + permuted weights -> 16
// consecutive cols/lane, coalesced stores; XOR-swizzled LDS staging.
// ---------------------------------------------------------------------------

typedef __attribute__((ext_vector_type(8))) __bf16 bf16x8;
typedef __attribute__((ext_vector_type(4))) float f32x4;
typedef __attribute__((ext_vector_type(8))) unsigned short ushort8v;
typedef __attribute__((ext_vector_type(4))) unsigned short ushort4v;

__device__ __forceinline__ float b2f(unsigned short u) {
  union { unsigned u; float f; } x; x.u = (unsigned)u << 16; return x.f;
}
__device__ __forceinline__ unsigned short f2b(float f) {
  union { float f; unsigned u; } x; x.f = f;
  unsigned r = x.u + 0x7fffu + ((x.u >> 16) & 1u);   // RNE
  return (unsigned short)(r >> 16);
}
__device__ __forceinline__ int xcd_swizzle(int orig, int nwg) {
  const int xcd = orig & 7, lin = orig >> 3;
  const int q = nwg >> 3, r8 = nwg & 7;
  return (xcd < r8 ? xcd * (q + 1) : r8 * (q + 1) + (xcd - r8) * q) + lin;
}
__device__ __forceinline__ void stage16(const void* g, void* lds_uniform) {
  __builtin_amdgcn_global_load_lds(
      (const __attribute__((address_space(1))) void*)g,
      (__attribute__((address_space(3))) void*)lds_uniform, 16, 0, 0);
}

// ============================ batch structs ================================
struct IB {
  const float4* a[3]; const float4* b[3]; const float4* c[3];
  unsigned short* xb[3];
  long long cum[4];
};
struct HB {
  const int* ei[3]; int E[3]; int cum[4];
  int* deg[3]; const int* rowptr[3]; int* srcs[3];
};
struct PB {
  const int* deg[3]; int* rowptr[3]; int N[3]; int nbcum[4];
};
struct GB {
  const unsigned short* A[3]; const unsigned short* BT[3];
  const float* bias[3]; void* C[3];
  int M[3]; int cum[4];
};
struct SB {
  const unsigned short* qkv[3]; const int* srcs[3]; const int* rowptr[3];
  float* sc[3]; float* pm[3]; float* ps[3];
  int N[3]; int cum[4];
};
struct MB {
  const float* pm[3]; const float* ps[3]; int nslots[3];
};
struct AB {
  const unsigned short* qkv[3]; const float* sc[3]; const int* srcs[3];
  const int* rowptr[3]; unsigned short* agg[3];
  int N[3]; int cum[4];
};
struct LB {
  const unsigned short* proj[3]; const float* g[3]; const float* bt[3];
  unsigned short* xb[3]; int N[3]; int cum[4];
};
__device__ __forceinline__ int find3(int b, const int* cum) {
  return (b >= cum[1]) + (b >= cum[2]);
}

// ======================= xb = bf16(a + b + c), batched =====================
__global__ __launch_bounds__(256) void init_b_kernel(IB ib)
{
  long long total = ib.cum[3];
  long long stride = (long long)gridDim.x * 256;
  for (long long i = (long long)blockIdx.x * 256 + threadIdx.x; i < total; i += stride) {
    int s = (i >= ib.cum[1]) + (i >= ib.cum[2]);
    long long j = i - ib.cum[s];
    float4 av = ib.a[s][j], bv = ib.b[s][j], cv = ib.c[s][j];
    ushort4v o;
    o.x = f2b(av.x + bv.x + cv.x); o.y = f2b(av.y + bv.y + cv.y);
    o.z = f2b(av.z + bv.z + cv.z); o.w = f2b(av.w + bv.w + cv.w);
    *(ushort4v*)(ib.xb[s] + j * 4) = o;
  }
}

// ===== weight transpose fp32[512][512] -> bf16 WT[perm(c)][r], all 27 ======
__global__ __launch_bounds__(256) void transpose_all_kernel(
    const float* W0, const float* W1, const float* W2, const float* Wh,
    unsigned short* WT)
{
  __shared__ float t[32][33];
  int z = blockIdx.z;
  const float* src = (z < 8)  ? W0 + (size_t)z * 262144
                   : (z < 16) ? W1 + (size_t)(z - 8) * 262144
                   : (z < 24) ? W2 + (size_t)(z - 16) * 262144
                              : Wh + (size_t)(z - 24) * 262144;
  unsigned short* dst = WT + (size_t)z * 262144;
  int bx = blockIdx.x * 32, by = blockIdx.y * 32;
  int tx = threadIdx.x, ty = threadIdx.y;   // block 32x8
  #pragma unroll
  for (int i = 0; i < 32; i += 8)
    t[ty + i][tx] = src[(size_t)(by + ty + i) * 512 + bx + tx];
  __syncthreads();
  #pragma unroll
  for (int i = 0; i < 32; i += 8) {
    int c = bx + ty + i;
    int p = (c & ~0x3C) | ((c & 0x30) >> 2) | ((c & 0x0C) << 2);
    dst[(size_t)p * 512 + by + tx] = f2b(t[tx][ty + i]);
  }
}

// ====== big bf16 GEMM (256x256, 8 waves, counted-vmcnt, barrier-light) =====
// LDS 160KB: Abuf[3] @ {0,32,64}KB, Bbuf[2] @ {96,128}KB. Tile t: B(t+1)
// issued early, A(t+2) issued mid-tile; ONLY boundary sync per K-tile:
// s_waitcnt vmcnt(4) lgkmcnt(0) + s_barrier (A(t+2) stays in flight).
// Intra-tile barriers removed (pacing-only): waves drift so MFMA of one
// wave overlaps ds_read of another.
template<int OUT_BF16>
__global__ __launch_bounds__(512, 2) void gemm_big_kernel(GB gb, int Ncols)
{
  constexpr int K = 512;
  __shared__ unsigned short smem[81920];   // 160 KB

  const int b = blockIdx.x;
  const int s = find3(b, gb.cum);
  const int wgid = xcd_swizzle(b - gb.cum[s], gb.cum[s + 1] - gb.cum[s]);
  const unsigned short* A  = gb.A[s];
  const unsigned short* BT = gb.BT[s];
  const float* bias = gb.bias[s];
  const int M = gb.M[s];

  const int tiles_n = Ncols >> 8;
  const int tm = wgid / tiles_n;
  const int tn = wgid - tm * tiles_n;
  const int row0 = tm << 8, col0 = tn << 8;
  const int lane = threadIdx.x & 63, wid = threadIdx.x >> 6;
  const int wr = (wid >> 2) << 7;
  const int wc = (wid & 3) << 6;

  f32x4 acc[8][4];
  #pragma unroll
  for (int i = 0; i < 8; ++i)
    #pragma unroll
    for (int j = 0; j < 4; ++j) acc[i][j] = (f32x4)0.f;

  // staging plan: 32 segs of 1KB per operand; wave owns segs (i<<3)|wid.
  int srow[4], scsw[4], sseg[4];
  #pragma unroll
  for (int i = 0; i < 4; ++i) {
    int seg = (i << 3) | wid;
    int idx = (seg << 6) | lane;
    int row = idx >> 3, ch = idx & 7;
    sseg[i] = seg; srow[i] = row; scsw[i] = ch ^ (row & 7);
  }

  #define STG_A(buf3, kb_, i)                                                 \
    { int ra = row0 + srow[i]; ra = (ra < M) ? ra : (M - 1);                  \
      stage16(A + (size_t)ra * K + (kb_) + (scsw[i] << 3),                    \
              smem + (buf3) * 16384 + (sseg[i] << 9)); }
  #define STG_B(buf2, kb_, i)                                                 \
    { int rb = col0 + srow[i];                                                \
      stage16(BT + (size_t)rb * K + (kb_) + (scsw[i] << 3),                   \
              smem + 49152 + (buf2) * 16384 + (sseg[i] << 9)); }

  // prologue: B(0), A(0), A(1) in flight; wait for B(0)+A(0) (oldest 8)
  STG_B(0, 0, 0) STG_B(0, 0, 1) STG_B(0, 0, 2) STG_B(0, 0, 3)
  STG_A(0, 0, 0) STG_A(0, 0, 1) STG_A(0, 0, 2) STG_A(0, 0, 3)
  STG_A(1, 64, 0) STG_A(1, 64, 1) STG_A(1, 64, 2) STG_A(1, 64, 3)
  asm volatile("s_waitcnt vmcnt(4)" ::: "memory");
  __builtin_amdgcn_s_barrier();

  const int lm = lane & 15;
  const int kbl = (lane >> 4) << 4;

  #pragma unroll
  for (int kt = 0; kt < 8; ++kt) {
    const char* Asb = (const char*)(smem + (kt % 3) * 16384);
    const char* Bsb = (const char*)(smem + 49152 + (kt & 1) * 16384);
    const int kb1 = (kt + 1) << 6, kb2 = (kt + 2) << 6;

    auto rdA = [&](int mi, int kk) -> bf16x8 {
      int r = wr + (mi << 4) + lm;
      int kb = (kk << 6) + kbl;
      return *(const bf16x8*)(Asb + (r << 7) + (kb ^ ((r & 7) << 4)));
    };
    auto rdB = [&](int ni, int kk) -> bf16x8 {
      int r = wc + (ni << 4) + lm;
      int kb = (kk << 6) + kbl;
      return *(const bf16x8*)(Bsb + (r << 7) + (kb ^ ((r & 7) << 4)));
    };

    bf16x8 av[4], bv[4];

    // ---- chunk 0: frags (mi 0-3, kk0) + B(kk0); issue B(t+1) stage
    #pragma unroll
    for (int i = 0; i < 4; ++i) { av[i] = rdA(i, 0); bv[i] = rdB(i, 0); }
    if (kt < 7) {
      STG_B((kt + 1) & 1, kb1, 0) STG_B((kt + 1) & 1, kb1, 1)
      STG_B((kt + 1) & 1, kb1, 2) STG_B((kt + 1) & 1, kb1, 3)
    }
    __builtin_amdgcn_s_setprio(1);
    #pragma unroll
    for (int mi = 0; mi < 4; ++mi)
      #pragma unroll
      for (int ni = 0; ni < 4; ++ni)
        acc[mi][ni] = __builtin_amdgcn_mfma_f32_16x16x32_bf16(
            bv[ni], av[mi], acc[mi][ni], 0, 0, 0);
    __builtin_amdgcn_s_setprio(0);

    // ---- chunk 1: frags (mi 4-7, kk0); issue A(t+2) stage
    #pragma unroll
    for (int i = 0; i < 4; ++i) av[i] = rdA(4 + i, 0);
    if (kt < 6) {
      STG_A((kt + 2) % 3, kb2, 0) STG_A((kt + 2) % 3, kb2, 1)
      STG_A((kt + 2) % 3, kb2, 2) STG_A((kt + 2) % 3, kb2, 3)
    }
    __builtin_amdgcn_s_setprio(1);
    #pragma unroll
    for (int mi = 0; mi < 4; ++mi)
      #pragma unroll
      for (int ni = 0; ni < 4; ++ni)
        acc[4 + mi][ni] = __builtin_amdgcn_mfma_f32_16x16x32_bf16(
            bv[ni], av[mi], acc[4 + mi][ni], 0, 0, 0);
    __builtin_amdgcn_s_setprio(0);

    // ---- chunk 2: frags (mi 0-3, kk1) + B(kk1)
    #pragma unroll
    for (int i = 0; i < 4; ++i) { av[i] = rdA(i, 1); bv[i] = rdB(i, 1); }
    __builtin_amdgcn_s_setprio(1);
    #pragma unroll
    for (int mi = 0; mi < 4; ++mi)
      #pragma unroll
      for (int ni = 0; ni < 4; ++ni)
        acc[mi][ni] = __builtin_amdgcn_mfma_f32_16x16x32_bf16(
            bv[ni], av[mi], acc[mi][ni], 0, 0, 0);
    __builtin_amdgcn_s_setprio(0);

    // ---- chunk 3: frags (mi 4-7, kk1)
    #pragma unroll
    for (int i = 0; i < 4; ++i) av[i] = rdA(4 + i, 1);
    __builtin_amdgcn_s_setprio(1);
    #pragma unroll
    for (int mi = 0; mi < 4; ++mi)
      #pragma unroll
      for (int ni = 0; ni < 4; ++ni)
        acc[4 + mi][ni] = __builtin_amdgcn_mfma_f32_16x16x32_bf16(
            bv[ni], av[mi], acc[4 + mi][ni], 0, 0, 0);
    __builtin_amdgcn_s_setprio(0);

    // ---- K-tile boundary: COUNTED wait — A(t+2)'s 4 loads stay in flight.
    if (kt < 6) {
      asm volatile("s_waitcnt vmcnt(4) lgkmcnt(0)" ::: "memory");
      __builtin_amdgcn_s_barrier();
    } else if (kt == 6) {
      asm volatile("s_waitcnt vmcnt(0) lgkmcnt(0)" ::: "memory");
      __builtin_amdgcn_s_barrier();
    }
    // kt == 7: epilogue follows; no LDS reuse, no wait needed.
  }
  #undef STG_A
  #undef STG_B

  const int mrow = lane & 15;
  const int t4 = (lane >> 4) << 4;
  float bsv[16];
  #pragma unroll
  for (int ni = 0; ni < 4; ++ni) {
    float4 bvv = *(const float4*)(bias + col0 + wc + t4 + (ni << 2));
    bsv[4*ni+0] = bvv.x; bsv[4*ni+1] = bvv.y; bsv[4*ni+2] = bvv.z; bsv[4*ni+3] = bvv.w;
  }

  if (OUT_BF16) {
    unsigned short* C = (unsigned short*)gb.C[s];
    #pragma unroll
    for (int mi = 0; mi < 8; ++mi) {
      int rowg = row0 + wr + (mi << 4) + mrow;
      if (rowg < M) {
        ushort8v o0, o1;
        #pragma unroll
        for (int r = 0; r < 4; ++r) {
          o0[r]     = f2b(acc[mi][0][r] + bsv[r]);
          o0[4 + r] = f2b(acc[mi][1][r] + bsv[4 + r]);
          o1[r]     = f2b(acc[mi][2][r] + bsv[8 + r]);
          o1[4 + r] = f2b(acc[mi][3][r] + bsv[12 + r]);
        }
        unsigned short* cp = C + (size_t)rowg * Ncols + col0 + wc + t4;
        *(ushort8v*)cp = o0;
        *(ushort8v*)(cp + 8) = o1;
      }
    }
  } else {
    float* C = (float*)gb.C[s];
    #pragma unroll
    for (int mi = 0; mi < 8; ++mi) {
      int rowg = row0 + wr + (mi << 4) + mrow;
      if (rowg < M) {
        float* cp = C + (size_t)rowg * Ncols + col0 + wc + t4;
        #pragma unroll
        for (int ni = 0; ni < 4; ++ni) {
          float4 v;
          v.x = acc[mi][ni][0] + bsv[4*ni+0];
          v.y = acc[mi][ni][1] + bsv[4*ni+1];
          v.z = acc[mi][ni][2] + bsv[4*ni+2];
          v.w = acc[mi][ni][3] + bsv[4*ni+3];
          *(float4*)(cp + (ni << 2)) = v;
        }
      }
    }
  }
}

// == small bf16 GEMM (128x128, 4 waves, 2-phase dbuf — round-7), batched ====
template<int OUT_BF16>
__global__ __launch_bounds__(256) void gemm_sm_kernel(GB gb, int Ncols)
{
  constexpr int K = 512;
  // double buffer: buf b at smem + b*16384 (As 8192 | Bs 8192 shorts), 64KB
  __shared__ unsigned short smem[32768];

  const int b = blockIdx.x;
  const int s = find3(b, gb.cum);
  const int wgid = xcd_swizzle(b - gb.cum[s], gb.cum[s + 1] - gb.cum[s]);
  const unsigned short* A  = gb.A[s];
  const unsigned short* BT = gb.BT[s];
  const float* bias = gb.bias[s];
  const int M = gb.M[s];

  const int tiles_n = Ncols >> 7;
  const int tm = wgid / tiles_n;
  const int tn = wgid - tm * tiles_n;
  const int row0 = tm << 7, col0 = tn << 7;
  const int lane = threadIdx.x & 63, wid = threadIdx.x >> 6;
  const int wm = (wid >> 1) << 6, wn = (wid & 1) << 6;

  f32x4 acc[4][4];
  #pragma unroll
  for (int i = 0; i < 4; ++i)
    #pragma unroll
    for (int j = 0; j < 4; ++j) acc[i][j] = (f32x4)0.f;

  int srow[4], scsw[4], sseg[4];
  #pragma unroll
  for (int i = 0; i < 4; ++i) {
    int seg = (i << 2) | wid;
    int idx = (seg << 6) | lane;
    int row = idx >> 3, ch = idx & 7;
    sseg[i] = seg; srow[i] = row; scsw[i] = ch ^ (row & 7);
  }

  #define STAGE_SM(buf, kb_)                                                  \
    _Pragma("unroll")                                                         \
    for (int i = 0; i < 4; ++i) {                                             \
      int ra = row0 + srow[i]; ra = (ra < M) ? ra : (M - 1);                  \
      stage16(A + (size_t)ra * K + (kb_) + (scsw[i] << 3),                    \
              smem + (buf) * 16384 + (sseg[i] << 9));                         \
      int rb = col0 + srow[i];                                                \
      stage16(BT + (size_t)rb * K + (kb_) + (scsw[i] << 3),                   \
              smem + (buf) * 16384 + 8192 + (sseg[i] << 9));                  \
    }

  STAGE_SM(0, 0)
  asm volatile("s_waitcnt vmcnt(0)" ::: "memory");
  __syncthreads();

  #pragma unroll
  for (int kt = 0; kt < 8; ++kt) {
    const int cur = kt & 1;
    if (kt < 7) {                      // issue next K-step's stage FIRST
      STAGE_SM(cur ^ 1, (kt + 1) << 6)
    }
    const unsigned short* As = smem + cur * 16384;
    const unsigned short* Bs = As + 8192;
    #pragma unroll
    for (int kk = 0; kk < 2; ++kk) {
      const int kb = (kk << 6) + ((lane >> 4) << 4);
      bf16x8 af[4], bfr[4];
      #pragma unroll
      for (int mi = 0; mi < 4; ++mi) {
        int r = wm + (mi << 4) + (lane & 15);
        af[mi] = *(const bf16x8*)((const char*)As + (r << 7) + (kb ^ ((r & 7) << 4)));
      }
      #pragma unroll
      for (int ni = 0; ni < 4; ++ni) {
        int r = wn + (ni << 4) + (lane & 15);
        bfr[ni] = *(const bf16x8*)((const char*)Bs + (r << 7) + (kb ^ ((r & 7) << 4)));
      }
      #pragma unroll
      for (int mi = 0; mi < 4; ++mi)
        #pragma unroll
        for (int ni = 0; ni < 4; ++ni)
          acc[mi][ni] = __builtin_amdgcn_mfma_f32_16x16x32_bf16(
              bfr[ni], af[mi], acc[mi][ni], 0, 0, 0);
    }
    // next buffer staged + everyone done reading cur before it's overwritten
    asm volatile("s_waitcnt vmcnt(0)" ::: "memory");
    __syncthreads();
  }
  #undef STAGE_SM

  const int mrow = lane & 15;
  const int t4 = (lane >> 4) << 4;
  float bsv[16];
  #pragma unroll
  for (int ni = 0; ni < 4; ++ni) {
    float4 bvv = *(const float4*)(bias + col0 + wn + t4 + (ni << 2));
    bsv[4*ni+0] = bvv.x; bsv[4*ni+1] = bvv.y; bsv[4*ni+2] = bvv.z; bsv[4*ni+3] = bvv.w;
  }

  if (OUT_BF16) {
    unsigned short* C = (unsigned short*)gb.C[s];
    #pragma unroll
    for (int mi = 0; mi < 4; ++mi) {
      int rowg = row0 + wm + (mi << 4) + mrow;
      if (rowg < M) {
        ushort8v o0, o1;
        #pragma unroll
        for (int r = 0; r < 4; ++r) {
          o0[r]     = f2b(acc[mi][0][r] + bsv[r]);
          o0[4 + r] = f2b(acc[mi][1][r] + bsv[4 + r]);
          o1[r]     = f2b(acc[mi][2][r] + bsv[8 + r]);
          o1[4 + r] = f2b(acc[mi][3][r] + bsv[12 + r]);
        }
        unsigned short* cp = C + (size_t)rowg * Ncols + col0 + wn + t4;
        *(ushort8v*)cp = o0;
        *(ushort8v*)(cp + 8) = o1;
      }
    }
  } else {
    float* C = (float*)gb.C[s];
    #pragma unroll
    for (int mi = 0; mi < 4; ++mi) {
      int rowg = row0 + wm + (mi << 4) + mrow;
      if (rowg < M) {
        float* cp = C + (size_t)rowg * Ncols + col0 + wn + t4;
        #pragma unroll
        for (int ni = 0; ni < 4; ++ni) {
          float4 v;
          v.x = acc[mi][ni][0] + bsv[4*ni+0];
          v.y = acc[mi][ni][1] + bsv[4*ni+1];
          v.z = acc[mi][ni][2] + bsv[4*ni+2];
          v.w = acc[mi][ni][3] + bsv[4*ni+3];
          *(float4*)(cp + (ni << 2)) = v;
        }
      }
    }
  }
}

// ====== CSR-ordered edge scores + fused ONLINE (max,sumexp), batched =======
__global__ __launch_bounds__(256) void scores_b_kernel(SB sb)
{
  int b = blockIdx.x;
  int s = find3(b, sb.cum);
  int lb = b - sb.cum[s];
  const unsigned short* qkv = sb.qkv[s];
  const int* srcs = sb.srcs[s];
  float* sc = sb.sc[s];
  int wid = threadIdx.x >> 6, lane = threadIdx.x & 63;
  int n = (lb << 2) | wid;
  float mx = -1e30f, sm = 0.f;
  if (n < sb.N[s]) {
    int beg = sb.rowptr[s][n], end = sb.rowptr[s][n + 1];
    if (beg < end) {
      ushort8v qv = *(const ushort8v*)(qkv + (size_t)n * 1536 + (lane << 3));
      float qf[8];
      #pragma unroll
      for (int j = 0; j < 8; ++j) qf[j] = b2f(qv[j]);
      int i = beg;
      for (; i + 2 <= end; i += 2) {       // 2-edge ILP
        int s0 = srcs[i], s1 = srcs[i + 1];
        ushort8v k0 = *(const ushort8v*)(qkv + (size_t)s0 * 1536 + 512 + (lane << 3));
        ushort8v k1 = *(const ushort8v*)(qkv + (size_t)s1 * 1536 + 512 + (lane << 3));
        float p0 = 0.f, p1 = 0.f;
        #pragma unroll
        for (int j = 0; j < 8; ++j) { p0 += qf[j] * b2f(k0[j]); p1 += qf[j] * b2f(k1[j]); }
        p0 += __shfl_xor(p0, 1); p1 += __shfl_xor(p1, 1);
        p0 += __shfl_xor(p0, 2); p1 += __shfl_xor(p1, 2);
        p0 += __shfl_xor(p0, 4); p1 += __shfl_xor(p1, 4);
        p0 *= 0.125f; p1 *= 0.125f;
        float nm = fmaxf(mx, fmaxf(p0, p1));
        sm = sm * __expf(mx - nm) + __expf(p0 - nm) + __expf(p1 - nm);
        mx = nm;
        if (!(lane & 7)) {
          sc[(size_t)i * 8 + (lane >> 3)] = p0;
          sc[(size_t)(i + 1) * 8 + (lane >> 3)] = p1;
        }
      }
      if (i < end) {
        int s0 = srcs[i];
        ushort8v k0 = *(const ushort8v*)(qkv + (size_t)s0 * 1536 + 512 + (lane << 3));
        float p0 = 0.f;
        #pragma unroll
        for (int j = 0; j < 8; ++j) p0 += qf[j] * b2f(k0[j]);
        p0 += __shfl_xor(p0, 1);
        p0 += __shfl_xor(p0, 2);
        p0 += __shfl_xor(p0, 4);
        p0 *= 0.125f;
        float nm = fmaxf(mx, p0);
        sm = sm * __expf(mx - nm) + __expf(p0 - nm);
        mx = nm;
        if (!(lane & 7)) sc[(size_t)i * 8 + (lane >> 3)] = p0;
      }
    }
  }
  if (!(lane & 7)) {
    size_t slot = ((size_t)lb << 2) | wid;
    sb.pm[s][slot * 8 + (lane >> 3)] = mx;
    sb.ps[s][slot * 8 + (lane >> 3)] = sm;
  }
}

// ============ (max,sum) pair block reduce ==================================
__device__ __forceinline__ void pair_reduce_block(
    float (&m)[8], float (&s)[8], float* redm, float* reds)
{
  int lane = threadIdx.x & 63, wid = threadIdx.x >> 6;
  #pragma unroll
  for (int h = 0; h < 8; ++h)
    #pragma unroll
    for (int off = 1; off < 64; off <<= 1) {
      float om = __shfl_xor(m[h], off);
      float os = __shfl_xor(s[h], off);
      float M = fmaxf(m[h], om);
      s[h] = s[h] * __expf(m[h] - M) + os * __expf(om - M);
      m[h] = M;
    }
  if (lane == 0) {
    #pragma unroll
    for (int h = 0; h < 8; ++h) { redm[h * 4 + wid] = m[h]; reds[h * 4 + wid] = s[h]; }
  }
  __syncthreads();
  if (threadIdx.x == 0) {
    #pragma unroll
    for (int h = 0; h < 8; ++h) {
      float M = redm[h * 4], S = reds[h * 4];
      #pragma unroll
      for (int w = 1; w < 4; ++w) {
        float om = redm[h * 4 + w], os = reds[h * 4 + w];
        float nM = fmaxf(M, om);
        S = S * __expf(M - nM) + os * __expf(om - nM);
        M = nM;
      }
      m[h] = M; s[h] = S;
    }
  }
}

// stage-1 parallel combine, batched: 256 blocks per stream (grid = 768)
__global__ __launch_bounds__(256) void gms_part_b_kernel(
    MB mb, float* pm2, float* ps2)
{
  __shared__ float redm[32], reds[32];
  int s = blockIdx.x >> 8, j = blockIdx.x & 255;
  const float* pm = mb.pm[s];
  const float* ps = mb.ps[s];
  float m[8], sv[8];
  #pragma unroll
  for (int h = 0; h < 8; ++h) { m[h] = -1e30f; sv[h] = 0.f; }
  for (int i = j * 256 + threadIdx.x; i < mb.nslots[s]; i += 65536) {
    #pragma unroll
    for (int h = 0; h < 8; ++h) {
      float mi = pm[(size_t)i * 8 + h], si = ps[(size_t)i * 8 + h];
      float M = fmaxf(m[h], mi);
      sv[h] = sv[h] * __expf(m[h] - M) + si * __expf(mi - M);
      m[h] = M;
    }
  }
  pair_reduce_block(m, sv, redm, reds);
  if (threadIdx.x == 0) {
    #pragma unroll
    for (int h = 0; h < 8; ++h) {
      pm2[(s * 256 + j) * 8 + h] = m[h];
      ps2[(s * 256 + j) * 8 + h] = sv[h];
    }
  }
}

// stage-2 final combine, batched: 3 blocks (one per stream)
__global__ __launch_bounds__(256) void gms_final_b_kernel(
    const float* pm2, const float* ps2, float* gmax, float* ginv)
{
  __shared__ float redm[32], reds[32];
  int s = blockIdx.x;
  float m[8], sv[8];
  #pragma unroll
  for (int h = 0; h < 8; ++h) {
    m[h]  = pm2[(s * 256 + threadIdx.x) * 8 + h];
    sv[h] = ps2[(s * 256 + threadIdx.x) * 8 + h];
  }
  pair_reduce_block(m, sv, redm, reds);
  if (threadIdx.x == 0) {
    #pragma unroll
    for (int h = 0; h < 8; ++h) { gmax[s * 8 + h] = m[h]; ginv[s * 8 + h] = 1.0f / sv[h]; }
  }
}

// =============================== CSR build, batched ========================
__global__ __launch_bounds__(256) void hist_b_kernel(HB hb)
{
  int b = blockIdx.x;
  int s = find3(b, hb.cum);
  int e = (b - hb.cum[s]) * 256 + threadIdx.x;
  if (e < hb.E[s]) atomicAdd(&hb.deg[s][hb.ei[s][hb.E[s] + e]], 1);
}

__global__ __launch_bounds__(1024) void scan_part_b_kernel(PB pb, int* bsums)
{
  __shared__ int wsum[16];
  int b = blockIdx.x;
  int s = (b >= pb.nbcum[1]) + (b >= pb.nbcum[2]);
  int lb = b - pb.nbcum[s];
  int i = lb * 1024 + threadIdx.x;
  int lane = threadIdx.x & 63, wid = threadIdx.x >> 6;
  int sv = (i < pb.N[s]) ? pb.deg[s][i] : 0;
  #pragma unroll
  for (int off = 1; off < 64; off <<= 1) {
    int t = __shfl_up(sv, off);
    if (lane >= off) sv += t;
  }
  if (lane == 63) wsum[wid] = sv;
  __syncthreads();
  if (threadIdx.x < 16) {
    int ws = wsum[threadIdx.x];
    #pragma unroll
    for (int off = 1; off < 16; off <<= 1) {
      int t = __shfl_up(ws, off);
      if (threadIdx.x >= off) ws += t;
    }
    wsum[threadIdx.x] = ws;
  }
  __syncthreads();
  if (wid > 0) sv += wsum[wid - 1];
  if (i < pb.N[s]) pb.rowptr[s][i + 1] = sv;
  if (threadIdx.x == 1023) bsums[s * 64 + lb] = sv;
}

__global__ __launch_bounds__(64) void scan_bsums_b_kernel(
    int* bsums, int nb0, int nb1, int nb2)
{
  int s = blockIdx.x;
  int nb = (s == 0) ? nb0 : (s == 1) ? nb1 : nb2;
  int* bs = bsums + s * 64;
  int lane = threadIdx.x;
  int v = (lane < nb) ? bs[lane] : 0;
  #pragma unroll
  for (int off = 1; off < 64; off <<= 1) {
    int t = __shfl_up(v, off);
    if (lane >= off) v += t;
  }
  int ex = __shfl_up(v, 1);
  if (lane == 0) ex = 0;
  if (lane < nb) bs[lane] = ex;     // exclusive offsets, in place
}

__global__ __launch_bounds__(1024) void scan_add_b_kernel(
    PB pb, const int* bsums)
{
  int b = blockIdx.x;
  int s = (b >= pb.nbcum[1]) + (b >= pb.nbcum[2]);
  int lb = b - pb.nbcum[s];
  int i = lb * 1024 + threadIdx.x;
  if (lb == 0 && threadIdx.x == 0) pb.rowptr[s][0] = 0;
  if (i < pb.N[s] && lb > 0) pb.rowptr[s][i + 1] += bsums[s * 64 + lb];
}

__global__ __launch_bounds__(256) void scatter_b_kernel(HB hb)
{
  int b = blockIdx.x;
  int s = find3(b, hb.cum);
  int e = (b - hb.cum[s]) * 256 + threadIdx.x;
  if (e < hb.E[s]) {
    const int* ei = hb.ei[s];
    int dst = ei[hb.E[s] + e];
    int pos = atomicAdd(&hb.deg[s][dst], 1);
    hb.srcs[s][hb.rowptr[s][dst] + pos] = ei[e];
  }
}

// == aggregate: agg[n] = sum_i exp(sc_i - gmax)*ginv * v[srcs[i]], batched ==
__global__ __launch_bounds__(256) void aggregate_b_kernel(
    AB ab, const float* gmaxg, const float* ginvg)
{
  int b = blockIdx.x;
  int s = find3(b, ab.cum);
  int lb = b - ab.cum[s];
  int wid = threadIdx.x >> 6, lane = threadIdx.x & 63;
  int n = (lb << 2) | wid;
  if (n >= ab.N[s]) return;
  const unsigned short* qkv = ab.qkv[s];
  const float* sc = ab.sc[s];
  const int* srcs = ab.srcs[s];
  int beg = ab.rowptr[s][n], end = ab.rowptr[s][n + 1];
  int h = lane >> 3;
  float gm  = gmaxg[s * 8 + h];
  float inv = ginvg[s * 8 + h];
  float acc[8] = {0.f,0.f,0.f,0.f,0.f,0.f,0.f,0.f};
  int i = beg;
  for (; i + 4 <= end; i += 4) {       // 4-edge ILP
    int s0 = srcs[i], s1 = srcs[i + 1], s2 = srcs[i + 2], s3 = srcs[i + 3];
    float w0 = __expf(sc[(size_t)i * 8 + h] - gm) * inv;
    float w1 = __expf(sc[(size_t)(i + 1) * 8 + h] - gm) * inv;
    float w2 = __expf(sc[(size_t)(i + 2) * 8 + h] - gm) * inv;
    float w3 = __expf(sc[(size_t)(i + 3) * 8 + h] - gm) * inv;
    ushort8v v0 = *(const ushort8v*)(qkv + (size_t)s0 * 1536 + 1024 + (lane << 3));
    ushort8v v1 = *(const ushort8v*)(qkv + (size_t)s1 * 1536 + 1024 + (lane << 3));
    ushort8v v2 = *(const ushort8v*)(qkv + (size_t)s2 * 1536 + 1024 + (lane << 3));
    ushort8v v3 = *(const ushort8v*)(qkv + (size_t)s3 * 1536 + 1024 + (lane << 3));
    #pragma unroll
    for (int j = 0; j < 8; ++j)
      acc[j] += (w0 * b2f(v0[j]) + w1 * b2f(v1[j]))
              + (w2 * b2f(v2[j]) + w3 * b2f(v3[j]));
  }
  for (; i < end; ++i) {
    int s0 = srcs[i];
    float w0 = __expf(sc[(size_t)i * 8 + h] - gm) * inv;
    ushort8v v0 = *(const ushort8v*)(qkv + (size_t)s0 * 1536 + 1024 + (lane << 3));
    #pragma unroll
    for (int j = 0; j < 8; ++j) acc[j] += w0 * b2f(v0[j]);
  }
  ushort8v o;
  #pragma unroll
  for (int j = 0; j < 8; ++j) o[j] = f2b(acc[j]);
  *(ushort8v*)(ab.agg[s] + (size_t)n * 512 + (lane << 3)) = o;
}

// ============== LN(proj + resid)*g + bt, bf16 residual, batched ============
__global__ __launch_bounds__(256) void ln_b_kernel(LB lb_)
{
  int b = blockIdx.x;
  int s = find3(b, lb_.cum);
  int lb = b - lb_.cum[s];
  int wid = threadIdx.x >> 6, lane = threadIdx.x & 63;
  int n = (lb << 2) | wid;
  if (n >= lb_.N[s]) return;
  size_t base = (size_t)n * 512 + (lane << 3);
  ushort8v pv = *(const ushort8v*)(lb_.proj[s] + base);
  ushort8v xv = *(const ushort8v*)(lb_.xb[s] + base);
  float y[8];
  #pragma unroll
  for (int j = 0; j < 8; ++j) y[j] = b2f(pv[j]) + b2f(xv[j]);
  float sum = 0.f;
  #pragma unroll
  for (int j = 0; j < 8; ++j) sum += y[j];
  #pragma unroll
  for (int off = 1; off < 64; off <<= 1) sum += __shfl_xor(sum, off);
  float mean = sum * (1.f / 512.f);
  float vs = 0.f;
  #pragma unroll
  for (int j = 0; j < 8; ++j) { float d = y[j] - mean; vs += d * d; }
  #pragma unroll
  for (int off = 1; off < 64; off <<= 1) vs += __shfl_xor(vs, off);
  float rstd = rsqrtf(vs * (1.f / 512.f) + 1e-5f);
  int gi = lane << 3;
  ushort8v ob;
  #pragma unroll
  for (int j = 0; j < 8; ++j)
    ob[j] = f2b((y[j] - mean) * rstd * lb_.g[s][gi + j] + lb_.bt[s][gi + j]);
  *(ushort8v*)(lb_.xb[s] + base) = ob;
}

// ================================ driver ====================================
extern "C" void kernel_launch(void* const* d_in, const int* in_sizes, int n_in,
                              void* d_out, int out_size, void* d_ws, size_t ws_size,
                              hipStream_t stream)
{
  (void)n_in; (void)out_size;
  const float* feat[3] = {(const float*)d_in[0], (const float*)d_in[1], (const float*)d_in[2]};
  const float* emb[3]  = {(const float*)d_in[3], (const float*)d_in[4], (const float*)d_in[5]};
  const float* pos[3]  = {(const float*)d_in[6], (const float*)d_in[7], (const float*)d_in[8]};
  const float* W[3]  = {(const float*)d_in[9],  (const float*)d_in[13], (const float*)d_in[17]};
  const float* Bb[3] = {(const float*)d_in[10], (const float*)d_in[14], (const float*)d_in[18]};
  const float* G[3]  = {(const float*)d_in[11], (const float*)d_in[15], (const float*)d_in[19]};
  const float* Bt[3] = {(const float*)d_in[12], (const float*)d_in[16], (const float*)d_in[20]};
  const float* headW = (const float*)d_in[21];
  const float* headB = (const float*)d_in[22];
  const int* ei[3] = {(const int*)d_in[23], (const int*)d_in[24], (const int*)d_in[25]};

  int Ns[3], Es[3];
  for (int s = 0; s < 3; ++s) { Ns[s] = in_sizes[s] / 512; Es[s] = in_sizes[23 + s] / 2; }

  long long Noff[4] = {0}, Eoff[4] = {0}, Roff[4] = {0}, Poff[4] = {0};
  for (int s = 0; s < 3; ++s) {
    Noff[s + 1] = Noff[s] + Ns[s];
    Eoff[s + 1] = Eoff[s] + Es[s];
    Roff[s + 1] = Roff[s] + Ns[s] + 1;
    Poff[s + 1] = Poff[s] + ((Ns[s] + 3) / 4) * 4;
  }

  char* base = (char*)d_ws;
  size_t off = 0;
  auto carve = [&](size_t bytes) -> char* {
    char* r = base + off;
    off += (bytes + 255) & ~(size_t)255;
    return r;
  };
  unsigned short* WT   = (unsigned short*)carve((size_t)27 * 262144 * 2);
  unsigned short* XB   = (unsigned short*)carve((size_t)Noff[3] * 512 * 2);
  unsigned short* QKV  = (unsigned short*)carve((size_t)Noff[3] * 1536 * 2);
  float*          SC   = (float*)carve((size_t)Eoff[3] * 8 * 4);
  unsigned short* AGG  = (unsigned short*)carve((size_t)Noff[3] * 512 * 2);
  int*   ROWPTR = (int*)carve((size_t)Roff[3] * 4);
  int*   DEG    = (int*)carve((size_t)Noff[3] * 4);
  int*   SRCS   = (int*)carve((size_t)Eoff[3] * 4);
  int*   BSUMS  = (int*)carve(3 * 64 * 4);
  float* PARTM  = (float*)carve((size_t)Poff[3] * 8 * 4);
  float* PARTS1 = (float*)carve((size_t)Poff[3] * 8 * 4);
  float* PARTM2 = (float*)carve(3 * 256 * 8 * 4);
  float* PARTS2 = (float*)carve(3 * 256 * 8 * 4);
  float* GMAX   = (float*)carve(256);
  float* GINV   = (float*)carve(256);
  if (off > ws_size) return;     // insufficient workspace: fail loudly

  unsigned short* XBs[3];  unsigned short* QKVs[3]; float* SCs[3];
  unsigned short* AGGs[3]; int* ROWPTRs[3]; int* DEGs[3]; int* SRCSs[3];
  float* PMs[3]; float* PSs[3];
  for (int s = 0; s < 3; ++s) {
    XBs[s]  = XB  + Noff[s] * 512;
    QKVs[s] = QKV + Noff[s] * 1536;
    SCs[s]  = SC  + Eoff[s] * 8;
    AGGs[s] = AGG + Noff[s] * 512;
    ROWPTRs[s] = ROWPTR + Roff[s];
    DEGs[s] = DEG + Noff[s];
    SRCSs[s] = SRCS + Eoff[s];
    PMs[s] = PARTM + Poff[s] * 8;
    PSs[s] = PARTS1 + Poff[s] * 8;
  }

  // 1) weights -> bf16 transposed + column-permuted (27 matrices, 1 launch)
  transpose_all_kernel<<<dim3(16, 16, 27), dim3(32, 8), 0, stream>>>(
      W[0], W[1], W[2], headW, WT);

  // 2) init (batched)
  IB ib;
  for (int s = 0; s < 3; ++s) {
    ib.a[s] = (const float4*)feat[s]; ib.b[s] = (const float4*)emb[s];
    ib.c[s] = (const float4*)pos[s];  ib.xb[s] = XBs[s];
  }
  ib.cum[0] = 0;
  for (int s = 0; s < 3; ++s) ib.cum[s + 1] = ib.cum[s] + (long long)Ns[s] * 128;
  init_b_kernel<<<2048, 256, 0, stream>>>(ib);

  // 3) CSR build (batched; one memset covers all streams)
  HB hb;
  hb.cum[0] = 0;
  for (int s = 0; s < 3; ++s) {
    hb.ei[s] = ei[s]; hb.E[s] = Es[s];
    hb.cum[s + 1] = hb.cum[s] + (Es[s] + 255) / 256;
    hb.deg[s] = DEGs[s]; hb.rowptr[s] = ROWPTRs[s]; hb.srcs[s] = SRCSs[s];
  }
  PB pb;
  pb.nbcum[0] = 0;
  for (int s = 0; s < 3; ++s) {
    pb.deg[s] = DEGs[s]; pb.rowptr[s] = ROWPTRs[s]; pb.N[s] = Ns[s];
    pb.nbcum[s + 1] = pb.nbcum[s] + (Ns[s] + 1023) / 1024;
  }
  hipMemsetAsync(DEG, 0, (size_t)Noff[3] * 4, stream);
  hist_b_kernel<<<hb.cum[3], 256, 0, stream>>>(hb);
  scan_part_b_kernel<<<pb.nbcum[3], 1024, 0, stream>>>(pb, BSUMS);
  scan_bsums_b_kernel<<<3, 64, 0, stream>>>(
      BSUMS, (Ns[0] + 1023) / 1024, (Ns[1] + 1023) / 1024, (Ns[2] + 1023) / 1024);
  scan_add_b_kernel<<<pb.nbcum[3], 1024, 0, stream>>>(pb, BSUMS);
  hipMemsetAsync(DEG, 0, (size_t)Noff[3] * 4, stream);
  scatter_b_kernel<<<hb.cum[3], 256, 0, stream>>>(hb);

  // shared batch geometry
  int nsbcum[4] = {0}, mtcum[4] = {0}, mtscum[4] = {0};
  for (int s = 0; s < 3; ++s) {
    nsbcum[s + 1] = nsbcum[s] + (Ns[s] + 3) / 4;
    mtcum[s + 1]  = mtcum[s]  + ((Ns[s] + 255) >> 8) * 6;    // big QKV (1536)
    mtscum[s + 1] = mtscum[s] + ((Ns[s] + 127) >> 7) * 4;    // small (512)
  }

  MB mb;
  for (int s = 0; s < 3; ++s) {
    mb.pm[s] = PMs[s]; mb.ps[s] = PSs[s];
    mb.nslots[s] = ((Ns[s] + 3) / 4) * 4;
  }

  // 4) layers (layer-major across streams)
  for (int l = 0; l < 2; ++l) {
    GB qg;
    for (int s = 0; s < 3; ++s) {
      qg.A[s] = XBs[s];
      qg.BT[s] = WT + (size_t)(s * 8 + l * 4) * 262144;
      qg.bias[s] = Bb[s] + (size_t)l * 2048;
      qg.C[s] = QKVs[s];
      qg.M[s] = Ns[s];
      qg.cum[s] = mtcum[s];
    }
    qg.cum[3] = mtcum[3];
    gemm_big_kernel<1><<<mtcum[3], 512, 0, stream>>>(qg, 1536);

    SB sb;
    for (int s = 0; s < 3; ++s) {
      sb.qkv[s] = QKVs[s]; sb.srcs[s] = SRCSs[s]; sb.rowptr[s] = ROWPTRs[s];
      sb.sc[s] = SCs[s]; sb.pm[s] = PMs[s]; sb.ps[s] = PSs[s];
      sb.N[s] = Ns[s]; sb.cum[s] = nsbcum[s];
    }
    sb.cum[3] = nsbcum[3];
    scores_b_kernel<<<nsbcum[3], 256, 0, stream>>>(sb);

    gms_part_b_kernel<<<768, 256, 0, stream>>>(mb, PARTM2, PARTS2);
    gms_final_b_kernel<<<3, 256, 0, stream>>>(PARTM2, PARTS2, GMAX, GINV);

    AB ab;
    for (int s = 0; s < 3; ++s) {
      ab.qkv[s] = QKVs[s]; ab.sc[s] = SCs[s]; ab.srcs[s] = SRCSs[s];
      ab.rowptr[s] = ROWPTRs[s]; ab.agg[s] = AGGs[s];
      ab.N[s] = Ns[s]; ab.cum[s] = nsbcum[s];
    }
    ab.cum[3] = nsbcum[3];
    aggregate_b_kernel<<<nsbcum[3], 256, 0, stream>>>(ab, GMAX, GINV);

    GB pg;
    for (int s = 0; s < 3; ++s) {
      pg.A[s] = AGGs[s];
      pg.BT[s] = WT + (size_t)(s * 8 + l * 4 + 3) * 262144;
      pg.bias[s] = Bb[s] + (size_t)(l * 2048 + 1536);
      pg.C[s] = QKVs[s];                      // PROJ aliases QKV (q/k/v dead)
      pg.M[s] = Ns[s];
      pg.cum[s] = mtscum[s];
    }
    pg.cum[3] = mtscum[3];
    gemm_sm_kernel<1><<<mtscum[3], 256, 0, stream>>>(pg, 512);

    LB lb;
    for (int s = 0; s < 3; ++s) {
      lb.proj[s] = QKVs[s]; lb.g[s] = G[s] + (size_t)l * 512;
      lb.bt[s] = Bt[s] + (size_t)l * 512; lb.xb[s] = XBs[s];
      lb.N[s] = Ns[s]; lb.cum[s] = nsbcum[s];
    }
    lb.cum[3] = nsbcum[3];
    ln_b_kernel<<<nsbcum[3], 256, 0, stream>>>(lb);
  }

  // 5) head (batched small GEMM, f32 out)
  GB hg;
  size_t out_off = 0;
  for (int s = 0; s < 3; ++s) {
    hg.A[s] = XBs[s];
    hg.BT[s] = WT + (size_t)(24 + s) * 262144;
    hg.bias[s] = headB + (size_t)s * 512;
    hg.C[s] = (float*)d_out + out_off;
    hg.M[s] = Ns[s];
    hg.cum[s] = mtscum[s];
    out_off += (size_t)Ns[s] * 512;
  }
  hg.cum[3] = mtscum[3];
  gemm_sm_kernel<0><<<mtscum[3], 256, 0, stream>>>(hg, 512);
}